// Round 1
// 531.389 us; speedup vs baseline: 1.3236x; 1.3236x over previous
//
#include <hip/hip_runtime.h>
#include <hip/hip_bf16.h>
#include <stdint.h>

#define M_TOT 8192   // B*S
#define N_TOT 4096   // D_OUT
#define K_TOT 4096   // D_IN

typedef __bf16 bf16x8 __attribute__((ext_vector_type(8)));
typedef float  f32x4  __attribute__((ext_vector_type(4)));

__device__ __forceinline__ uint16_t f2bf_rne(float f) {
  uint32_t u = __float_as_uint(f);
  u += 0x7fffu + ((u >> 16) & 1u);
  return (uint16_t)(u >> 16);
}

// ternary weight: (wp>0) - (wn<=0) in bf16 bits: 1.0=0x3F80, -1.0=0xBF80
__device__ __forceinline__ uint32_t tern(float p, float n) {
  bool pp = p > 0.0f, nn = n > 0.0f;
  return pp ? (nn ? 0x3F80u : 0u) : (nn ? 0u : 0xBF80u);
}

// ---- preprocess 1: x fp32 -> bf16 bits (8 elems/thread) ---- (unchanged this round)
__global__ __launch_bounds__(256) void cast_x_kernel(const float4* __restrict__ x,
                                                     uint4* __restrict__ out) {
  int t = blockIdx.x * 256 + threadIdx.x;
  float4 a = x[2 * t], b = x[2 * t + 1];
  uint4 o;
  o.x = (uint32_t)f2bf_rne(a.x) | ((uint32_t)f2bf_rne(a.y) << 16);
  o.y = (uint32_t)f2bf_rne(a.z) | ((uint32_t)f2bf_rne(a.w) << 16);
  o.z = (uint32_t)f2bf_rne(b.x) | ((uint32_t)f2bf_rne(b.y) << 16);
  o.w = (uint32_t)f2bf_rne(b.z) | ((uint32_t)f2bf_rne(b.w) << 16);
  out[t] = o;
}

// ---- preprocess 2: W = (wp>0)-(wn<=0) as bf16 bits ---- (unchanged this round)
__global__ __launch_bounds__(256) void ternarize_kernel(const float4* __restrict__ wp,
                                                        const float4* __restrict__ wn,
                                                        uint4* __restrict__ out) {
  int t = blockIdx.x * 256 + threadIdx.x;
  float4 p0 = wp[2 * t], p1 = wp[2 * t + 1];
  float4 n0 = wn[2 * t], n1 = wn[2 * t + 1];
  uint4 o;
  o.x = tern(p0.x, n0.x) | (tern(p0.y, n0.y) << 16);
  o.y = tern(p0.z, n0.z) | (tern(p0.w, n0.w) << 16);
  o.z = tern(p1.x, n1.x) | (tern(p1.y, n1.y) << 16);
  o.w = tern(p1.z, n1.z) | (tern(p1.w, n1.w) << 16);
  out[t] = o;
}

// ============================================================================
// GEMM: C[M,N] = Xb[M,K] * Wb[N,K]^T, bf16 MFMA 16x16x32.
// 256x256 tile, BK=64, 512 threads = 8 waves (2M x 4N), per-wave C = 128x64.
// 8-phase schedule (2 barriers/phase, counted vmcnt(8), setprio around MFMA).
//
// LDS 128 KiB, 8 regions of 16 KiB:  off = AB*65536 + buf*16384 + khalf*32768
//   A.k0.b0=0      A.k0.b1=16384  A.k1.b0=32768  A.k1.b1=49152
//   B.k0.b0=65536  B.k0.b1=81920  B.k1.b0=98304  B.k1.b1=114688
// Region inner layout: row (0..255) * 64B, 4 x 16B chunks, chunk swizzle
//   phys = logical ^ ((row>>1)&3)  (measured 0 bank conflicts at this geometry).
// global_load_lds writes linearly (wave-uniform dst + lane*16), so the swizzle
// is applied by permuting the per-lane GLOBAL source chunk; ds_read applies the
// same XOR. Reads use vaddr = inner(+buf via XOR-flip per tile) + imm khalf.
//
// Staging schedule (uniform for all t; source offsets clamped so tail tiles
// re-stage the last valid k-half into dead regions):
//   ph0: stage (t+1).A.k1   ph1: stage (t+1).B.k1   [vmcnt(8) at ph1 end]
//   ph2: stage (t+2).A.k0   ph3: stage (t+2).B.k0   [vmcnt(8) at ph3 end]
// Each region is last READ >=1 barrier before its stage is issued, and each
// read's data was vmcnt-retired (exactly) one phase earlier + barrier.
// ============================================================================

#define STAGE_HALF(SP0, SP1, DSTOFF)                                              \
  do {                                                                            \
    __builtin_amdgcn_global_load_lds(                                             \
        (const __attribute__((address_space(1))) unsigned int*)(SP0),             \
        (__attribute__((address_space(3))) unsigned int*)(smem + (DSTOFF) + lds0),\
        16, 0, 0);                                                                \
    __builtin_amdgcn_global_load_lds(                                             \
        (const __attribute__((address_space(1))) unsigned int*)(SP1),             \
        (__attribute__((address_space(3))) unsigned int*)(smem + (DSTOFF) + lds1),\
        16, 0, 0);                                                                \
  } while (0)

__global__ __launch_bounds__(512, 2) void gemm_tern_kernel(const uint16_t* __restrict__ Xb,
                                                           const uint16_t* __restrict__ Wb,
                                                           float* __restrict__ C) {
  __shared__ __align__(16) char smem[131072];
  const int tid  = threadIdx.x;
  const int wave = tid >> 6;
  const int lane = tid & 63;
  const int lh   = lane & 15, lq = lane >> 4;
  const int wm   = wave >> 2;   // 0..1
  const int wn   = wave & 3;    // 0..3

  // XCD-aware swizzle: 512 blocks, 8 XCDs, 64 consecutive per XCD (bijective).
  const int id  = blockIdx.x;
  const int swz = (id & 7) * 64 + (id >> 3);
  const int bn  = swz & 15;   // 0..15
  const int bm  = swz >> 4;   // 0..31

  // fragment ds_read offsets (inner, buf0); flipped ^16384 per tile
  const int p16 = ((lq ^ ((lh >> 1) & 3)) << 4);
  int aoffs[8], boffs[4];
#pragma unroll
  for (int i = 0; i < 8; ++i) aoffs[i] = (wm * 128 + i * 16 + lh) * 64 + p16;
#pragma unroll
  for (int j = 0; j < 4; ++j) boffs[j] = 65536 + (wn * 64 + j * 16 + lh) * 64 + p16;

  // staging: per thread 2 x 16B per half-region; pre-swizzled global source
  const int lds0 = wave * 2048;
  const int lds1 = lds0 + 1024;
  const char *srcA0, *srcA1, *srcB0, *srcB1;
  {
    int o0 = lds0 + lane * 16, o1 = lds1 + lane * 16;
    int r0 = o0 >> 6, r1 = o1 >> 6;
    int c0 = ((o0 >> 4) & 3) ^ ((r0 >> 1) & 3);
    int c1 = ((o1 >> 4) & 3) ^ ((r1 >> 1) & 3);
    srcA0 = (const char*)Xb + (size_t)(bm * 256 + r0) * (K_TOT * 2) + c0 * 16;
    srcA1 = (const char*)Xb + (size_t)(bm * 256 + r1) * (K_TOT * 2) + c1 * 16;
    srcB0 = (const char*)Wb + (size_t)(bn * 256 + r0) * (K_TOT * 2) + c0 * 16;
    srcB1 = (const char*)Wb + (size_t)(bn * 256 + r1) * (K_TOT * 2) + c1 * 16;
  }

  f32x4 acc[8][4];
#pragma unroll
  for (int i = 0; i < 8; ++i)
#pragma unroll
    for (int j = 0; j < 4; ++j) acc[i][j] = (f32x4){0.f, 0.f, 0.f, 0.f};

  // ---- prologue: tile0 {A,B}x{k0,k1}, tile1 {A,B}.k0  (12 loads/wave) ----
  STAGE_HALF(srcA0, srcA1, 0);                 // t0 A.k0 b0
  STAGE_HALF(srcB0, srcB1, 65536);             // t0 B.k0 b0
  STAGE_HALF(srcA0 + 64, srcA1 + 64, 32768);   // t0 A.k1 b0
  STAGE_HALF(srcB0 + 64, srcB1 + 64, 98304);   // t0 B.k1 b0
  STAGE_HALF(srcA0 + 128, srcA1 + 128, 16384); // t1 A.k0 b1
  STAGE_HALF(srcB0 + 128, srcB1 + 128, 81920); // t1 B.k0 b1
  asm volatile("s_waitcnt vmcnt(4)" ::: "memory");  // tile0 fully resident
  __builtin_amdgcn_s_barrier();
  asm volatile("" ::: "memory");

  for (int t = 0; t < 64; ++t) {
    const int curb = (t & 1) * 16384;
    const int nxtb = 16384 - curb;
    int offk1 = t * 128 + 192; if (offk1 > 8128) offk1 = 8128;  // (t+1) khalf1
    int offk0 = t * 128 + 256; if (offk0 > 8128) offk0 = 8128;  // (t+2) khalf0
    bf16x8 af[4], bfr[4];

    // ---------- phase 0: Mhalf0 x khalf0 ----------
#pragma unroll
    for (int i = 0; i < 4; ++i) af[i] = *(const bf16x8*)(smem + aoffs[i]);
#pragma unroll
    for (int j = 0; j < 4; ++j) bfr[j] = *(const bf16x8*)(smem + boffs[j]);
    STAGE_HALF(srcA0 + offk1, srcA1 + offk1, nxtb + 32768);      // (t+1).A.k1
    __builtin_amdgcn_s_barrier();
    asm volatile("s_waitcnt lgkmcnt(0)" ::: "memory");
    __builtin_amdgcn_sched_barrier(0);
    __builtin_amdgcn_s_setprio(1);
#pragma unroll
    for (int i = 0; i < 4; ++i)
#pragma unroll
      for (int j = 0; j < 4; ++j)
        acc[i][j] = __builtin_amdgcn_mfma_f32_16x16x32_bf16(af[i], bfr[j], acc[i][j], 0, 0, 0);
    __builtin_amdgcn_s_setprio(0);
    __builtin_amdgcn_sched_barrier(0);
    __builtin_amdgcn_s_barrier();
    asm volatile("" ::: "memory");

    // ---------- phase 1: Mhalf1 x khalf0 (reuse B k0 frags) ----------
#pragma unroll
    for (int i = 0; i < 4; ++i) af[i] = *(const bf16x8*)(smem + aoffs[4 + i]);
    STAGE_HALF(srcB0 + offk1, srcB1 + offk1, 98304 + nxtb);      // (t+1).B.k1
    __builtin_amdgcn_s_barrier();
    asm volatile("s_waitcnt lgkmcnt(0)" ::: "memory");
    __builtin_amdgcn_sched_barrier(0);
    __builtin_amdgcn_s_setprio(1);
#pragma unroll
    for (int i = 0; i < 4; ++i)
#pragma unroll
      for (int j = 0; j < 4; ++j)
        acc[4 + i][j] = __builtin_amdgcn_mfma_f32_16x16x32_bf16(af[i], bfr[j], acc[4 + i][j], 0, 0, 0);
    __builtin_amdgcn_s_setprio(0);
    asm volatile("s_waitcnt vmcnt(8)" ::: "memory");  // cur khalf1 resident
    __builtin_amdgcn_sched_barrier(0);
    __builtin_amdgcn_s_barrier();
    asm volatile("" ::: "memory");

    // ---------- phase 2: Mhalf0 x khalf1 ----------
#pragma unroll
    for (int i = 0; i < 4; ++i) af[i] = *(const bf16x8*)(smem + aoffs[i] + 32768);
#pragma unroll
    for (int j = 0; j < 4; ++j) bfr[j] = *(const bf16x8*)(smem + boffs[j] + 32768);
    STAGE_HALF(srcA0 + offk0, srcA1 + offk0, curb);              // (t+2).A.k0
    __builtin_amdgcn_s_barrier();
    asm volatile("s_waitcnt lgkmcnt(0)" ::: "memory");
    __builtin_amdgcn_sched_barrier(0);
    __builtin_amdgcn_s_setprio(1);
#pragma unroll
    for (int i = 0; i < 4; ++i)
#pragma unroll
      for (int j = 0; j < 4; ++j)
        acc[i][j] = __builtin_amdgcn_mfma_f32_16x16x32_bf16(af[i], bfr[j], acc[i][j], 0, 0, 0);
    __builtin_amdgcn_s_setprio(0);
    __builtin_amdgcn_sched_barrier(0);
    __builtin_amdgcn_s_barrier();
    asm volatile("" ::: "memory");

    // ---------- phase 3: Mhalf1 x khalf1 ----------
#pragma unroll
    for (int i = 0; i < 4; ++i) af[i] = *(const bf16x8*)(smem + aoffs[4 + i] + 32768);
    STAGE_HALF(srcB0 + offk0, srcB1 + offk0, 65536 + curb);      // (t+2).B.k0
    __builtin_amdgcn_s_barrier();
    asm volatile("s_waitcnt lgkmcnt(0)" ::: "memory");
    __builtin_amdgcn_sched_barrier(0);
    __builtin_amdgcn_s_setprio(1);
#pragma unroll
    for (int i = 0; i < 4; ++i)
#pragma unroll
      for (int j = 0; j < 4; ++j)
        acc[4 + i][j] = __builtin_amdgcn_mfma_f32_16x16x32_bf16(af[i], bfr[j], acc[4 + i][j], 0, 0, 0);
    __builtin_amdgcn_s_setprio(0);
    asm volatile("s_waitcnt vmcnt(8)" ::: "memory");  // next-tile khalf0 resident
    __builtin_amdgcn_sched_barrier(0);
    __builtin_amdgcn_s_barrier();
    asm volatile("" ::: "memory");

    // flip ds_read offsets to the other buffer
#pragma unroll
    for (int i = 0; i < 8; ++i) aoffs[i] ^= 16384;
#pragma unroll
    for (int j = 0; j < 4; ++j) boffs[j] ^= 16384;
  }

  asm volatile("s_waitcnt vmcnt(0)" ::: "memory");  // drain tail dummy stages

  // epilogue: C/D layout col = lane&15, row = quad*4 + reg
  const size_t base_m = (size_t)bm * 256 + wm * 128;
  const size_t base_n = (size_t)bn * 256 + wn * 64;
#pragma unroll
  for (int i = 0; i < 8; ++i) {
#pragma unroll
    for (int j = 0; j < 4; ++j) {
      size_t m0 = base_m + i * 16 + lq * 4;
      size_t n  = base_n + j * 16 + lh;
      float* p = C + m0 * N_TOT + n;
#pragma unroll
      for (int r = 0; r < 4; ++r) p[(size_t)r * N_TOT] = acc[i][j][r];
    }
  }
}

extern "C" void kernel_launch(void* const* d_in, const int* in_sizes, int n_in,
                              void* d_out, int out_size, void* d_ws, size_t ws_size,
                              hipStream_t stream) {
  const float* x  = (const float*)d_in[0];
  const float* wp = (const float*)d_in[1];
  const float* wn = (const float*)d_in[2];
  float* y = (float*)d_out;

  uint16_t* Xb = (uint16_t*)d_ws;                       // 8192*4096 bf16 = 64 MiB
  uint16_t* Wb = Xb + (size_t)M_TOT * K_TOT;            // 4096*4096 bf16 = 32 MiB

  cast_x_kernel<<<(M_TOT * (size_t)K_TOT) / 2048, 256, 0, stream>>>(
      (const float4*)x, (uint4*)Xb);
  ternarize_kernel<<<(N_TOT * (size_t)K_TOT) / 2048, 256, 0, stream>>>(
      (const float4*)wp, (const float4*)wn, (uint4*)Wb);

  gemm_tern_kernel<<<dim3(512), dim3(512), 0, stream>>>(Xb, Wb, y);
}

// Round 2
// 526.890 us; speedup vs baseline: 1.3349x; 1.0085x over previous
//
#include <hip/hip_runtime.h>
#include <hip/hip_bf16.h>
#include <stdint.h>

#define M_TOT 8192   // B*S
#define N_TOT 4096   // D_OUT
#define K_TOT 4096   // D_IN

typedef __bf16 bf16x8 __attribute__((ext_vector_type(8)));
typedef float  f32x4  __attribute__((ext_vector_type(4)));

__device__ __forceinline__ uint16_t f2bf_rne(float f) {
  uint32_t u = __float_as_uint(f);
  u += 0x7fffu + ((u >> 16) & 1u);
  return (uint16_t)(u >> 16);
}

// ternary weight: (wp>0) - (wn<=0) in bf16 bits: 1.0=0x3F80, -1.0=0xBF80
__device__ __forceinline__ uint32_t tern(float p, float n) {
  bool pp = p > 0.0f, nn = n > 0.0f;
  return pp ? (nn ? 0x3F80u : 0u) : (nn ? 0u : 0xBF80u);
}

// ---- fused preprocess: blocks [0,16384) cast x; [16384,24576) ternarize W ----
__global__ __launch_bounds__(256) void prep_kernel(const float4* __restrict__ x,
                                                   uint4* __restrict__ Xb4,
                                                   const float4* __restrict__ wp,
                                                   const float4* __restrict__ wn,
                                                   uint4* __restrict__ Wb4) {
  int b = blockIdx.x;
  if (b < 16384) {
    int t = b * 256 + (int)threadIdx.x;
    float4 a = x[2 * t], c = x[2 * t + 1];
    uint4 o;
    o.x = (uint32_t)f2bf_rne(a.x) | ((uint32_t)f2bf_rne(a.y) << 16);
    o.y = (uint32_t)f2bf_rne(a.z) | ((uint32_t)f2bf_rne(a.w) << 16);
    o.z = (uint32_t)f2bf_rne(c.x) | ((uint32_t)f2bf_rne(c.y) << 16);
    o.w = (uint32_t)f2bf_rne(c.z) | ((uint32_t)f2bf_rne(c.w) << 16);
    Xb4[t] = o;
  } else {
    int t = (b - 16384) * 256 + (int)threadIdx.x;
    float4 p0 = wp[2 * t], p1 = wp[2 * t + 1];
    float4 n0 = wn[2 * t], n1 = wn[2 * t + 1];
    uint4 o;
    o.x = tern(p0.x, n0.x) | (tern(p0.y, n0.y) << 16);
    o.y = tern(p0.z, n0.z) | (tern(p0.w, n0.w) << 16);
    o.z = tern(p1.x, n1.x) | (tern(p1.y, n1.y) << 16);
    o.w = tern(p1.z, n1.z) | (tern(p1.w, n1.w) << 16);
    Wb4[t] = o;
  }
}

// ============================================================================
// GEMM: C[M,N] = Xb[M,K] * Wb[N,K]^T, bf16 MFMA 16x16x32.
// 256x256 tile, BK=64, 512 threads = 8 waves (2M x 4N), per-wave C = 128x64.
// 8-phase schedule + FRAGMENT DOUBLE-BUFFERING: phase p issues phase p+1's
// ds_reads inside p's MFMA window; compiler emits counted lgkmcnt leaving the
// prefetch outstanding (no explicit lgkmcnt(0) drain any more).
//
// LDS 128 KiB, 8 regions of 16 KiB:  off = AB*65536 + buf*16384 + khalf*32768
// Region rows: 256 x 64B (K=32), chunk swizzle phys = logical ^ ((row>>1)&3),
// applied on the global SOURCE side (DMA dst linear) and on ds_read addrs.
//
// vmcnt(6) at END of ph0 and ph2 (before bar2): FIFO retirement analysis —
//   at t.ph0-end outstanding = {t.Bk1, t+1.Ak0, t+1.Bk0, t+1.Ak1} + t.Ak1
//   -> vmcnt(6) retires t.Ak1 & t.Bk1, exactly what ph1's early reads (t.k1)
//   need, and bar2 makes all waves' DMA visible before those reads.
//   at t.ph2-end -> retires t+1.Ak0 & t+1.Bk0 for ph3's early reads (t+1.k0).
// Every staged region's last reader finished >=1 barrier before its DMA.
// ============================================================================

#define GLDS(SRC, DST)                                                        \
  __builtin_amdgcn_global_load_lds(                                           \
      (const __attribute__((address_space(1))) unsigned int*)(SRC),           \
      (__attribute__((address_space(3))) unsigned int*)(DST), 16, 0, 0)

#define STAGE_HALF(BASE, OFF, DSTOFF)                                         \
  do {                                                                        \
    GLDS((BASE) + loff0 + (OFF), smem + (DSTOFF) + lds0);                     \
    GLDS((BASE) + loff1 + (OFF), smem + (DSTOFF) + lds1);                     \
  } while (0)

#define FENCE() asm volatile("" ::: "memory")

__global__ __launch_bounds__(512, 2) void gemm_tern_kernel(const uint16_t* __restrict__ Xb,
                                                           const uint16_t* __restrict__ Wb,
                                                           float* __restrict__ C) {
  __shared__ __align__(16) char smem[131072];
  const int tid  = threadIdx.x;
  const int wave = tid >> 6;
  const int lane = tid & 63;
  const int lh   = lane & 15, lq = lane >> 4;
  const int wm   = wave >> 2;   // 0..1
  const int wn   = wave & 3;    // 0..3

  // XCD-aware swizzle: 512 blocks, 8 XCDs, 64 consecutive per XCD (bijective).
  const int id  = blockIdx.x;
  const int swz = (id & 7) * 64 + (id >> 3);
  const int bn  = swz & 15;   // 0..15
  const int bm  = swz >> 4;   // 0..31

  // fragment ds_read offsets (inner, buf0); flipped ^16384 per tile
  const int p16 = ((lq ^ ((lh >> 1) & 3)) << 4);
  int aoffs[8], boffs[4];
#pragma unroll
  for (int i = 0; i < 8; ++i) aoffs[i] = (wm * 128 + i * 16 + lh) * 64 + p16;
#pragma unroll
  for (int j = 0; j < 4; ++j) boffs[j] = 65536 + (wn * 64 + j * 16 + lh) * 64 + p16;

  // staging: per thread 2 x 16B per half-region; pre-swizzled per-lane offset,
  // uniform SGPR bases (saves address VGPRs).
  const int lds0 = wave * 2048;
  const int lds1 = lds0 + 1024;
  uint32_t loff0, loff1;
  {
    int o0 = lds0 + lane * 16, o1 = lds1 + lane * 16;
    int r0 = o0 >> 6, r1 = o1 >> 6;
    int c0 = ((o0 >> 4) & 3) ^ ((r0 >> 1) & 3);
    int c1 = ((o1 >> 4) & 3) ^ ((r1 >> 1) & 3);
    loff0 = (uint32_t)r0 * (K_TOT * 2) + (uint32_t)c0 * 16;
    loff1 = (uint32_t)r1 * (K_TOT * 2) + (uint32_t)c1 * 16;
  }
  const char* Abase = (const char*)Xb + (size_t)bm * 256 * (K_TOT * 2);
  const char* Bbase = (const char*)Wb + (size_t)bn * 256 * (K_TOT * 2);

  f32x4 acc[8][4];
#pragma unroll
  for (int i = 0; i < 8; ++i)
#pragma unroll
    for (int j = 0; j < 4; ++j) acc[i][j] = (f32x4){0.f, 0.f, 0.f, 0.f};

  // ---- prologue: tile0 {A,B}x{k0,k1}, tile1 {A,B}.k0  (12 loads/wave) ----
  STAGE_HALF(Abase, 0, 0);            // t0 A.k0 b0
  STAGE_HALF(Bbase, 0, 65536);        // t0 B.k0 b0
  STAGE_HALF(Abase, 64, 32768);       // t0 A.k1 b0
  STAGE_HALF(Bbase, 64, 98304);       // t0 B.k1 b0
  STAGE_HALF(Abase, 128, 16384);      // t1 A.k0 b1
  STAGE_HALF(Bbase, 128, 81920);      // t1 B.k0 b1
  asm volatile("s_waitcnt vmcnt(4)" ::: "memory");  // tile0 fully resident
  __builtin_amdgcn_s_barrier();
  FENCE();

  // fragment registers (loop-carried, static indexing only)
  bf16x8 a0[4], a1[4], a2[4], a3[4], b0[4], b1[4];
#pragma unroll
  for (int i = 0; i < 4; ++i) a0[i] = *(const bf16x8*)(smem + aoffs[i]);
#pragma unroll
  for (int j = 0; j < 4; ++j) b0[j] = *(const bf16x8*)(smem + boffs[j]);

  for (int t = 0; t < 64; ++t) {
    const int curb = (t & 1) * 16384;
    const int nxtb = 16384 - curb;
    int offk1 = t * 128 + 192; if (offk1 > 8128) offk1 = 8128;  // (t+1) khalf1
    int offk0 = t * 128 + 256; if (offk0 > 8128) offk0 = 8128;  // (t+2) khalf0

    // ---------- phase 0: Mhalf0 x khalf0 (a0,b0) ----------
    STAGE_HALF(Abase, offk1, nxtb + 32768);            // (t+1).A.k1
    __builtin_amdgcn_s_barrier();
    FENCE();
#pragma unroll
    for (int i = 0; i < 4; ++i) a1[i] = *(const bf16x8*)(smem + aoffs[4 + i]);  // ph1 frags
    __builtin_amdgcn_s_setprio(1);
#pragma unroll
    for (int i = 0; i < 4; ++i)
#pragma unroll
      for (int j = 0; j < 4; ++j)
        acc[i][j] = __builtin_amdgcn_mfma_f32_16x16x32_bf16(a0[i], b0[j], acc[i][j], 0, 0, 0);
    __builtin_amdgcn_s_setprio(0);
    asm volatile("s_waitcnt vmcnt(6)" ::: "memory");   // t.k1 (A&B) resident
    __builtin_amdgcn_s_barrier();
    FENCE();

    // ---------- phase 1: Mhalf1 x khalf0 (a1,b0) ----------
    STAGE_HALF(Bbase, offk1, nxtb + 98304);            // (t+1).B.k1
    __builtin_amdgcn_s_barrier();
    FENCE();
#pragma unroll
    for (int i = 0; i < 4; ++i) a2[i] = *(const bf16x8*)(smem + aoffs[i] + 32768);  // ph2
#pragma unroll
    for (int j = 0; j < 4; ++j) b1[j] = *(const bf16x8*)(smem + boffs[j] + 32768);
    __builtin_amdgcn_s_setprio(1);
#pragma unroll
    for (int i = 0; i < 4; ++i)
#pragma unroll
      for (int j = 0; j < 4; ++j)
        acc[4 + i][j] = __builtin_amdgcn_mfma_f32_16x16x32_bf16(a1[i], b0[j], acc[4 + i][j], 0, 0, 0);
    __builtin_amdgcn_s_setprio(0);
    __builtin_amdgcn_s_barrier();
    FENCE();

    // ---------- phase 2: Mhalf0 x khalf1 (a2,b1) ----------
    STAGE_HALF(Abase, offk0, curb);                    // (t+2).A.k0
    __builtin_amdgcn_s_barrier();
    FENCE();
#pragma unroll
    for (int i = 0; i < 4; ++i) a3[i] = *(const bf16x8*)(smem + aoffs[4 + i] + 32768);  // ph3
    __builtin_amdgcn_s_setprio(1);
#pragma unroll
    for (int i = 0; i < 4; ++i)
#pragma unroll
      for (int j = 0; j < 4; ++j)
        acc[i][j] = __builtin_amdgcn_mfma_f32_16x16x32_bf16(a2[i], b1[j], acc[i][j], 0, 0, 0);
    __builtin_amdgcn_s_setprio(0);
    asm volatile("s_waitcnt vmcnt(6)" ::: "memory");   // (t+1).k0 (A&B) resident
    __builtin_amdgcn_s_barrier();
    FENCE();

    // ---------- phase 3: Mhalf1 x khalf1 (a3,b1) ----------
    STAGE_HALF(Bbase, offk0, 65536 + curb);            // (t+2).B.k0
    __builtin_amdgcn_s_barrier();
    FENCE();
#pragma unroll
    for (int i = 0; i < 4; ++i) a0[i] = *(const bf16x8*)(smem + (aoffs[i] ^ 16384));      // next ph0
#pragma unroll
    for (int j = 0; j < 4; ++j) b0[j] = *(const bf16x8*)(smem + (boffs[j] ^ 16384));
    __builtin_amdgcn_s_setprio(1);
#pragma unroll
    for (int i = 0; i < 4; ++i)
#pragma unroll
      for (int j = 0; j < 4; ++j)
        acc[4 + i][j] = __builtin_amdgcn_mfma_f32_16x16x32_bf16(a3[i], b1[j], acc[4 + i][j], 0, 0, 0);
    __builtin_amdgcn_s_setprio(0);
    __builtin_amdgcn_s_barrier();
    FENCE();

    // flip ds_read offsets to the other buffer
#pragma unroll
    for (int i = 0; i < 8; ++i) aoffs[i] ^= 16384;
#pragma unroll
    for (int j = 0; j < 4; ++j) boffs[j] ^= 16384;
  }

  asm volatile("s_waitcnt vmcnt(0)" ::: "memory");  // drain tail dummy stages

  // epilogue: C/D layout col = lane&15, row = quad*4 + reg
  const size_t base_m = (size_t)bm * 256 + wm * 128;
  const size_t base_n = (size_t)bn * 256 + wn * 64;
#pragma unroll
  for (int i = 0; i < 8; ++i) {
#pragma unroll
    for (int j = 0; j < 4; ++j) {
      size_t m0 = base_m + i * 16 + lq * 4;
      size_t n  = base_n + j * 16 + lh;
      float* p = C + m0 * N_TOT + n;
#pragma unroll
      for (int r = 0; r < 4; ++r) p[(size_t)r * N_TOT] = acc[i][j][r];
    }
  }
}

extern "C" void kernel_launch(void* const* d_in, const int* in_sizes, int n_in,
                              void* d_out, int out_size, void* d_ws, size_t ws_size,
                              hipStream_t stream) {
  const float* x  = (const float*)d_in[0];
  const float* wp = (const float*)d_in[1];
  const float* wn = (const float*)d_in[2];
  float* y = (float*)d_out;

  uint16_t* Xb = (uint16_t*)d_ws;                       // 8192*4096 bf16 = 64 MiB
  uint16_t* Wb = Xb + (size_t)M_TOT * K_TOT;            // 4096*4096 bf16 = 32 MiB

  prep_kernel<<<24576, 256, 0, stream>>>((const float4*)x, (uint4*)Xb,
                                         (const float4*)wp, (const float4*)wn,
                                         (uint4*)Wb);

  gemm_tern_kernel<<<dim3(512), dim3(512), 0, stream>>>(Xb, Wb, y);
}